// Round 1
// baseline (1151.599 us; speedup 1.0000x reference)
//
#include <hip/hip_runtime.h>
#include <stdint.h>

// ---------------- constants ----------------
#define NN    2048          // nodes
#define BB    16            // batch
#define CC    64            // in channels
#define TT    12            // time
#define OO    64            // out channels
#define ED    10            // embed dim
#define JJ    12288         // B*T*C  (j = (b*T+t)*C + c)
#define NJ    25165824      // NN*JJ
#define MBT   192           // B*T rows of per-node GEMM
#define KC    192           // 3*C contraction of per-node GEMM

typedef __attribute__((ext_vector_type(8))) short short8;   // 8 bf16 = 4 VGPR
typedef __attribute__((ext_vector_type(4))) float f32x4;

__device__ __forceinline__ unsigned short f2bf(float x) {
    union { float f; unsigned int u; } v; v.f = x;
    unsigned int r = (v.u + 0x7FFFu + ((v.u >> 16) & 1u)) >> 16;
    return (unsigned short)r;
}
__device__ __forceinline__ float bf2f(unsigned short h) {
    union { unsigned int u; float f; } v; v.u = ((unsigned int)h) << 16;
    return v.f;
}
__device__ __forceinline__ void async_cp16(const void* g, void* l) {
    __builtin_amdgcn_global_load_lds(
        (const __attribute__((address_space(1))) void*)(uintptr_t)g,
        (__attribute__((address_space(3))) void*)(uintptr_t)l, 16, 0, 0);
}

// ---------------- K1: A = softmax(relu(E E^T)) row-wise -> bf16 ----------------
__global__ __launch_bounds__(256) void k_softmax_A(const float* __restrict__ E,
                                                   unsigned short* __restrict__ Abf) {
    int n = blockIdx.x, tid = threadIdx.x;
    __shared__ float row[NN];
    __shared__ float red[256];
    float en[ED];
#pragma unroll
    for (int d = 0; d < ED; ++d) en[d] = E[n * ED + d];
    float mx = 0.0f;  // relu => values >= 0
    for (int m = tid; m < NN; m += 256) {
        float s = 0.f;
#pragma unroll
        for (int d = 0; d < ED; ++d) s += en[d] * E[m * ED + d];
        s = fmaxf(s, 0.0f);
        row[m] = s;
        mx = fmaxf(mx, s);
    }
    red[tid] = mx; __syncthreads();
    for (int s = 128; s; s >>= 1) { if (tid < s) red[tid] = fmaxf(red[tid], red[tid + s]); __syncthreads(); }
    mx = red[0]; __syncthreads();
    float sum = 0.f;
    for (int m = tid; m < NN; m += 256) { float e = __expf(row[m] - mx); row[m] = e; sum += e; }
    red[tid] = sum; __syncthreads();
    for (int s = 128; s; s >>= 1) { if (tid < s) red[tid] += red[tid + s]; __syncthreads(); }
    float inv = 1.0f / red[0];
    for (int m = tid; m < NN; m += 256) Abf[(size_t)n * NN + m] = f2bf(row[m] * inv);
}

// ---------------- K2: At[w][v] = support[v][w] -> bf16 ----------------
__global__ void k_trans_bf(const float* __restrict__ src, unsigned short* __restrict__ dst) {
    __shared__ float t[32][33];
    int tx = threadIdx.x, ty = threadIdx.y;     // (32, 8)
    int x0 = blockIdx.x * 32, y0 = blockIdx.y * 32;
#pragma unroll
    for (int i = 0; i < 4; ++i)
        t[ty + i * 8][tx] = src[(size_t)(y0 + ty + i * 8) * NN + x0 + tx];
    __syncthreads();
#pragma unroll
    for (int i = 0; i < 4; ++i)
        dst[(size_t)(x0 + ty + i * 8) * NN + y0 + tx] = f2bf(t[tx][ty + i * 8]);
}

// ---------------- K3: X2[n][(b*T+t)*C+c] = x[b][c][n][t] -> bf16 ----------------
__global__ __launch_bounds__(256) void k_make_X2(const float* __restrict__ x,
                                                 unsigned short* __restrict__ X2) {
    int idx = blockIdx.x * 256 + threadIdx.x;   // < NJ
    int n = idx / JJ;
    int r = idx - n * JJ;
    int bt = r >> 6;
    int c = r & 63;
    int b = bt / TT;
    int t = bt - b * TT;
    X2[idx] = f2bf(x[(((size_t)b * CC + c) * NN + n) * TT + t]);
}

// ---------------- K4: bf16 MFMA GEMM  Out[m][j] = alpha*sum_k Am[m][k]*Bm[k][j] (- Csub) ----------------
// M=K=2048, Ncols=JJ. grid (96,16), block 256 (4 waves, 64x64 wave tiles).
__global__ __launch_bounds__(256) void k_gemm(const unsigned short* __restrict__ Am,
                                              const unsigned short* __restrict__ Bm,
                                              unsigned short* __restrict__ Out,
                                              const unsigned short* __restrict__ Csub,
                                              float alpha) {
    __shared__ __align__(16) unsigned short lA[128 * 32];       // [m][k] no pad (lds-DMA)
    __shared__ __align__(16) unsigned short lB[128 * 40];       // [j][k] pad->40
    int tid = threadIdx.x, lane = tid & 63, wv = tid >> 6;
    int m0 = blockIdx.y * 128, j0 = blockIdx.x * 128;
    int wm = (wv >> 1) * 64, wn = (wv & 1) * 64;
    f32x4 zero = {0.f, 0.f, 0.f, 0.f};
    f32x4 acc[4][4];
#pragma unroll
    for (int a = 0; a < 4; ++a)
#pragma unroll
        for (int b = 0; b < 4; ++b) acc[a][b] = zero;

    int bj = (tid >> 4) * 8;       // 0..120  (j within tile)
    int bk = (tid & 15) * 2;       // 0..30   (k pair within tile)
    int q = lane >> 4, l15 = lane & 15;

    for (int kt = 0; kt < 64; ++kt) {
        int k0 = kt * 32;
        __syncthreads();
        // A tile: 128x32 via global_load_lds (16B per lane)
#pragma unroll
        for (int c = 0; c < 2; ++c) {
            int rowA = (wv + 4 * c) * 16 + (lane >> 2);
            int kkA = (lane & 3) * 8;
            async_cp16(Am + (size_t)(m0 + rowA) * 2048 + k0 + kkA,
                       &lA[(size_t)(wv + 4 * c) * 512 + lane * 8]);
        }
        // B tile: read 2 k-rows x 8 j, write transposed pairs as dwords
        {
            const unsigned short* g0 = Bm + (size_t)(k0 + bk) * JJ + j0 + bj;
            uint4 r0 = *(const uint4*)g0;
            uint4 r1 = *(const uint4*)(g0 + JJ);
            unsigned int* lB32 = (unsigned int*)lB;
            const unsigned int* p0 = &r0.x;
            const unsigned int* p1 = &r1.x;
#pragma unroll
            for (int i = 0; i < 8; ++i) {
                unsigned int lo = (i & 1) ? (p0[i >> 1] >> 16) : (p0[i >> 1] & 0xFFFFu);
                unsigned int hi = (i & 1) ? (p1[i >> 1] >> 16) : (p1[i >> 1] & 0xFFFFu);
                lB32[((bj + i) * 40 + bk) >> 1] = lo | (hi << 16);
            }
        }
        __syncthreads();
        short8 af[4], bfr[4];
#pragma unroll
        for (int tm = 0; tm < 4; ++tm)
            af[tm] = *(const short8*)&lA[(wm + tm * 16 + l15) * 32 + q * 8];
#pragma unroll
        for (int tn = 0; tn < 4; ++tn)
            bfr[tn] = *(const short8*)&lB[(wn + tn * 16 + l15) * 40 + q * 8];
#pragma unroll
        for (int tm = 0; tm < 4; ++tm)
#pragma unroll
            for (int tn = 0; tn < 4; ++tn)
                acc[tm][tn] = __builtin_amdgcn_mfma_f32_16x16x32_bf16(af[tm], bfr[tn], acc[tm][tn], 0, 0, 0);
    }
    // epilogue: Out[m][j] bf16, optional  alpha*acc - Csub
#pragma unroll
    for (int tm = 0; tm < 4; ++tm) {
#pragma unroll
        for (int tn = 0; tn < 4; ++tn) {
            int mm = m0 + wm + tm * 16 + q * 4;
            int jj = j0 + wn + tn * 16 + l15;
#pragma unroll
            for (int r = 0; r < 4; ++r) {
                size_t oidx = (size_t)(mm + r) * JJ + jj;
                float v = alpha * acc[tm][tn][r];
                if (Csub) v -= bf2f(Csub[oidx]);
                Out[oidx] = f2bf(v);
            }
        }
    }
}

// ---------------- K5/K6: per-node [192 x 192] @ [192 x 64] MFMA GEMM ----------------
// branch 0: x_av  (sources X2,Y1,Y2; W_n = sum_d E[n,d]*Wp[d]; bias = E[n]*bias_pool)
// branch 1: x_gcn (sources X2,Z1,Z2; W = mlp_w; bias = mlp_b)
__global__ __launch_bounds__(256) void k_node(const unsigned short* __restrict__ S0,
                                              const unsigned short* __restrict__ S1,
                                              const unsigned short* __restrict__ S2,
                                              const float* __restrict__ E,
                                              const float* __restrict__ Wp,
                                              const float* __restrict__ bias_pool,
                                              const float* __restrict__ mlp_w,
                                              const float* __restrict__ mlp_b,
                                              float* __restrict__ out,
                                              int branch) {
    int n = blockIdx.x, tid = threadIdx.x, lane = tid & 63, wv = tid >> 6;
    __shared__ __align__(16) unsigned short lW[64 * 200];   // W^T: [o][kappa] pad->200
    __shared__ __align__(16) unsigned short lS[192 * 72];   // one source: [m][i] pad->72
    __shared__ float lBias[64];
    int q = lane >> 4, l15 = lane & 15;

    if (branch == 0) {
        float en[ED];
#pragma unroll
        for (int d = 0; d < ED; ++d) en[d] = E[n * ED + d];
        for (int idx = tid; idx < KC * OO; idx += 256) {
            int o = idx & 63, kap = idx >> 6;                  // kap = k*64+i
            float s = 0.f;
#pragma unroll
            for (int d = 0; d < ED; ++d) s += en[d] * Wp[((size_t)d * KC + kap) * OO + o];
            lW[o * 200 + kap] = f2bf(s);
        }
        if (tid < 64) {
            float s = 0.f;
#pragma unroll
            for (int d = 0; d < ED; ++d) s += en[d] * bias_pool[d * OO + tid];
            lBias[tid] = s;
        }
    } else {
        for (int idx = tid; idx < KC * OO; idx += 256) {
            int o = idx & 63, kap = idx >> 6;
            lW[o * 200 + kap] = f2bf(mlp_w[kap * OO + o]);
        }
        if (tid < 64) lBias[tid] = mlp_b[tid];
    }

    f32x4 zero = {0.f, 0.f, 0.f, 0.f};
    f32x4 acc[3][4];
#pragma unroll
    for (int a = 0; a < 3; ++a)
#pragma unroll
        for (int b = 0; b < 4; ++b) acc[a][b] = zero;

    const unsigned short* Ss[3] = { S0 + (size_t)n * JJ, S1 + (size_t)n * JJ, S2 + (size_t)n * JJ };

    for (int s = 0; s < 3; ++s) {
        __syncthreads();
        // stage source row: 12288 bf16 -> lS[m][i] (pad 72)
#pragma unroll
        for (int v = 0; v < 6; ++v) {
            int e8 = (v * 256 + tid) * 8;
            int m = e8 >> 6, i = e8 & 63;
            *(short8*)&lS[m * 72 + i] = *(const short8*)&Ss[s][e8];
        }
        __syncthreads();
#pragma unroll
        for (int h = 0; h < 2; ++h) {
            short8 af[3], bfr[4];
#pragma unroll
            for (int tm = 0; tm < 3; ++tm)
                af[tm] = *(const short8*)&lS[(wv * 48 + tm * 16 + l15) * 72 + h * 32 + q * 8];
#pragma unroll
            for (int tn = 0; tn < 4; ++tn)
                bfr[tn] = *(const short8*)&lW[(tn * 16 + l15) * 200 + s * 64 + h * 32 + q * 8];
#pragma unroll
            for (int tm = 0; tm < 3; ++tm)
#pragma unroll
                for (int tn = 0; tn < 4; ++tn)
                    acc[tm][tn] = __builtin_amdgcn_mfma_f32_16x16x32_bf16(af[tm], bfr[tn], acc[tm][tn], 0, 0, 0);
        }
    }
    // epilogue: out[b][o][n][t] fp32, m = b*T+t
#pragma unroll
    for (int tm = 0; tm < 3; ++tm) {
#pragma unroll
        for (int tn = 0; tn < 4; ++tn) {
            int o = tn * 16 + l15;
#pragma unroll
            for (int r = 0; r < 4; ++r) {
                int m = wv * 48 + tm * 16 + q * 4 + r;
                int b = m / TT, t = m - b * TT;
                out[(((size_t)b * OO + o) * NN + n) * TT + t] = acc[tm][tn][r] + lBias[o];
            }
        }
    }
}

// ---------------- launch ----------------
extern "C" void kernel_launch(void* const* d_in, const int* in_sizes, int n_in,
                              void* d_out, int out_size, void* d_ws, size_t ws_size,
                              hipStream_t stream) {
    const float* x         = (const float*)d_in[0];
    const float* node_emb  = (const float*)d_in[1];
    const float* support   = (const float*)d_in[2];
    const float* wpool     = (const float*)d_in[3];
    const float* bpool     = (const float*)d_in[4];
    const float* mlp_w     = (const float*)d_in[5];
    const float* mlp_b     = (const float*)d_in[6];
    float* out             = (float*)d_out;

    unsigned short* Abf = (unsigned short*)d_ws;                 // 8 MB
    unsigned short* Atb = Abf + (size_t)NN * NN;                 // 8 MB
    unsigned short* X2  = Atb + (size_t)NN * NN;                 // 48 MB
    unsigned short* Y1  = X2 + (size_t)NJ;
    unsigned short* Y2  = Y1 + (size_t)NJ;
    unsigned short* Z1  = Y2 + (size_t)NJ;
    unsigned short* Z2  = Z1 + (size_t)NJ;                       // total 256 MB

    // prep
    k_softmax_A<<<NN, 256, 0, stream>>>(node_emb, Abf);
    k_trans_bf<<<dim3(64, 64), dim3(32, 8), 0, stream>>>(support, Atb);
    k_make_X2<<<NJ / 256, 256, 0, stream>>>(x, X2);

    // big GEMMs
    dim3 gg(96, 16);
    k_gemm<<<gg, 256, 0, stream>>>(Abf, X2, Y1, nullptr, 1.0f);
    k_gemm<<<gg, 256, 0, stream>>>(Abf, Y1, Y2, X2, 2.0f);       // Y2 = 2*A*Y1 - X2
    k_gemm<<<gg, 256, 0, stream>>>(Atb, X2, Z1, nullptr, 1.0f);
    k_gemm<<<gg, 256, 0, stream>>>(Atb, Z1, Z2, nullptr, 1.0f);

    // per-node epilogues
    k_node<<<NN, 256, 0, stream>>>(X2, Y1, Y2, node_emb, wpool, bpool, nullptr, nullptr,
                                   out, 0);
    k_node<<<NN, 256, 0, stream>>>(X2, Z1, Z2, nullptr, nullptr, nullptr, mlp_w, mlp_b,
                                   out + (size_t)NJ, 1);
}

// Round 2
// 1111.565 us; speedup vs baseline: 1.0360x; 1.0360x over previous
//
#include <hip/hip_runtime.h>
#include <stdint.h>

// ---------------- constants ----------------
#define NN    2048          // nodes
#define BB    16            // batch
#define CC    64            // in channels
#define TT    12            // time
#define OO    64            // out channels
#define ED    10            // embed dim
#define JJ    12288         // B*T*C  (j = (b*T+t)*C + c)
#define NJ    25165824      // NN*JJ
#define KC    192           // 3*C contraction of per-node GEMM

typedef __attribute__((ext_vector_type(8))) short short8;   // 8 bf16 = 4 VGPR
typedef __attribute__((ext_vector_type(4))) float f32x4;

__device__ __forceinline__ unsigned short f2bf(float x) {
    union { float f; unsigned int u; } v; v.f = x;
    unsigned int r = (v.u + 0x7FFFu + ((v.u >> 16) & 1u)) >> 16;
    return (unsigned short)r;
}
__device__ __forceinline__ float bf2f(unsigned short h) {
    union { unsigned int u; float f; } v; v.u = ((unsigned int)h) << 16;
    return v.f;
}
__device__ __forceinline__ void async_cp16(const void* g, void* l) {
    __builtin_amdgcn_global_load_lds(
        (const __attribute__((address_space(1))) void*)(uintptr_t)g,
        (__attribute__((address_space(3))) void*)(uintptr_t)l, 16, 0, 0);
}

// ---------------- K1: A = softmax(relu(E E^T)) row-wise -> bf16 ----------------
__global__ __launch_bounds__(256) void k_softmax_A(const float* __restrict__ E,
                                                   unsigned short* __restrict__ Abf) {
    int n = blockIdx.x, tid = threadIdx.x;
    __shared__ float row[NN];
    __shared__ float red[256];
    float en[ED];
#pragma unroll
    for (int d = 0; d < ED; ++d) en[d] = E[n * ED + d];
    float mx = 0.0f;  // relu => values >= 0
    for (int m = tid; m < NN; m += 256) {
        float s = 0.f;
#pragma unroll
        for (int d = 0; d < ED; ++d) s += en[d] * E[m * ED + d];
        s = fmaxf(s, 0.0f);
        row[m] = s;
        mx = fmaxf(mx, s);
    }
    red[tid] = mx; __syncthreads();
    for (int s = 128; s; s >>= 1) { if (tid < s) red[tid] = fmaxf(red[tid], red[tid + s]); __syncthreads(); }
    mx = red[0]; __syncthreads();
    float sum = 0.f;
    for (int m = tid; m < NN; m += 256) { float e = __expf(row[m] - mx); row[m] = e; sum += e; }
    red[tid] = sum; __syncthreads();
    for (int s = 128; s; s >>= 1) { if (tid < s) red[tid] += red[tid + s]; __syncthreads(); }
    float inv = 1.0f / red[0];
    for (int m = tid; m < NN; m += 256) Abf[(size_t)n * NN + m] = f2bf(row[m] * inv);
}

// ---------------- K2: At[w][v] = support[v][w] -> bf16 ----------------
__global__ void k_trans_bf(const float* __restrict__ src, unsigned short* __restrict__ dst) {
    __shared__ float t[32][33];
    int tx = threadIdx.x, ty = threadIdx.y;     // (32, 8)
    int x0 = blockIdx.x * 32, y0 = blockIdx.y * 32;
#pragma unroll
    for (int i = 0; i < 4; ++i)
        t[ty + i * 8][tx] = src[(size_t)(y0 + ty + i * 8) * NN + x0 + tx];
    __syncthreads();
#pragma unroll
    for (int i = 0; i < 4; ++i)
        dst[(size_t)(x0 + ty + i * 8) * NN + y0 + tx] = f2bf(t[tx][ty + i * 8]);
}

// ---------------- K3: X2[n][(b*T+t)*C+c] = x[b][c][n][t] -> bf16 ----------------
__global__ __launch_bounds__(256) void k_make_X2(const float* __restrict__ x,
                                                 unsigned short* __restrict__ X2) {
    int idx = blockIdx.x * 256 + threadIdx.x;   // < NJ
    int n = idx / JJ;
    int r = idx - n * JJ;
    int bt = r >> 6;
    int c = r & 63;
    int b = bt / TT;
    int t = bt - b * TT;
    X2[idx] = f2bf(x[(((size_t)b * CC + c) * NN + n) * TT + t]);
}

// ---------------- K3b: bf16 tiled transpose  dst[j][n] = src[n][j] ----------------
// src: [2048][12288], dst: [12288][2048]. 64x64 tiles, block 256.
__global__ __launch_bounds__(256) void k_trans16(const unsigned short* __restrict__ src,
                                                 unsigned short* __restrict__ dst) {
    __shared__ unsigned short t[64][72];     // pad 72 shorts
    int tid = threadIdx.x;
    int j0 = blockIdx.x * 64, n0 = blockIdx.y * 64;
    int r = tid >> 3, c8 = (tid & 7) * 8;    // 32 rows per pass, 8 shorts per thread
#pragma unroll
    for (int it = 0; it < 2; ++it) {
        int rr = r + it * 32;
        *(short8*)&t[rr][c8] = *(const short8*)&src[(size_t)(n0 + rr) * JJ + j0 + c8];
    }
    __syncthreads();
#pragma unroll
    for (int it = 0; it < 2; ++it) {
        int rr = r + it * 32;                // j-row within tile
        unsigned short v[8];
#pragma unroll
        for (int u = 0; u < 8; ++u) v[u] = t[c8 + u][rr];
        *(short8*)&dst[(size_t)(j0 + rr) * NN + n0 + c8] = *(short8*)v;
    }
}

// ---------------- K4: bf16 MFMA GEMM  Out[m][j] = alpha*sum_k Am[m][k]*Bt[j][k] (- Csub) ----------------
// Am: [2048][2048] row-major (k contig). Bt: [12288][2048] row-major (k contig).
// Out: [2048][12288] (j contig). grid (96,16), block 256 (4 waves, 64x64 wave tiles).
__global__ __launch_bounds__(256) void k_gemm(const unsigned short* __restrict__ Am,
                                              const unsigned short* __restrict__ Bt,
                                              unsigned short* __restrict__ Out,
                                              const unsigned short* __restrict__ Csub,
                                              float alpha) {
    __shared__ __align__(16) unsigned short lA[128 * 32];       // [m][k] no pad (lds-DMA)
    __shared__ __align__(16) unsigned short lB[128 * 32];       // [j][k] no pad (lds-DMA)
    int tid = threadIdx.x, lane = tid & 63, wv = tid >> 6;
    int m0 = blockIdx.y * 128, j0 = blockIdx.x * 128;
    int wm = (wv >> 1) * 64, wn = (wv & 1) * 64;
    f32x4 zero = {0.f, 0.f, 0.f, 0.f};
    f32x4 acc[4][4];
#pragma unroll
    for (int a = 0; a < 4; ++a)
#pragma unroll
        for (int b = 0; b < 4; ++b) acc[a][b] = zero;

    int q = lane >> 4, l15 = lane & 15;
    int rA = lane >> 2;                // row within 16-row group
    int cA = (lane & 3) * 8;           // k offset (shorts)

    const unsigned short* gA = Am + (size_t)(m0 + (lane >> 2)) * 2048 + cA;
    const unsigned short* gB = Bt + (size_t)(j0 + (lane >> 2)) * 2048 + cA;

    for (int kt = 0; kt < 64; ++kt) {
        int k0 = kt * 32;
        __syncthreads();
#pragma unroll
        for (int c = 0; c < 2; ++c) {
            int g = wv + 4 * c;        // 16-row group 0..7
            async_cp16(gA + (size_t)g * 16 * 2048 + k0, &lA[g * 512 + lane * 8]);
            async_cp16(gB + (size_t)g * 16 * 2048 + k0, &lB[g * 512 + lane * 8]);
        }
        __syncthreads();
        short8 af[4], bfr[4];
#pragma unroll
        for (int tm = 0; tm < 4; ++tm)
            af[tm] = *(const short8*)&lA[(wm + tm * 16 + l15) * 32 + q * 8];
#pragma unroll
        for (int tn = 0; tn < 4; ++tn)
            bfr[tn] = *(const short8*)&lB[(wn + tn * 16 + l15) * 32 + q * 8];
#pragma unroll
        for (int tm = 0; tm < 4; ++tm)
#pragma unroll
            for (int tn = 0; tn < 4; ++tn)
                acc[tm][tn] = __builtin_amdgcn_mfma_f32_16x16x32_bf16(af[tm], bfr[tn], acc[tm][tn], 0, 0, 0);
    }
    // epilogue: Out[m][j] bf16, optional  alpha*acc - Csub
#pragma unroll
    for (int tm = 0; tm < 4; ++tm) {
#pragma unroll
        for (int tn = 0; tn < 4; ++tn) {
            int mm = m0 + wm + tm * 16 + q * 4;
            int jj = j0 + wn + tn * 16 + l15;
#pragma unroll
            for (int r = 0; r < 4; ++r) {
                size_t oidx = (size_t)(mm + r) * JJ + jj;
                float v = alpha * acc[tm][tn][r];
                if (Csub) v -= bf2f(Csub[oidx]);
                Out[oidx] = f2bf(v);
            }
        }
    }
}

// ---------------- K5/K6: per-node [192 x 192] @ [192 x 64] MFMA GEMM ----------------
// branch 0: x_av  (sources X2,Y1,Y2; W_n = sum_d E[n,d]*Wp[d]; bias = E[n]*bias_pool)
// branch 1: x_gcn (sources X2,Z1,Z2; W = mlp_w; bias = mlp_b)
__global__ __launch_bounds__(256) void k_node(const unsigned short* __restrict__ S0,
                                              const unsigned short* __restrict__ S1,
                                              const unsigned short* __restrict__ S2,
                                              const float* __restrict__ E,
                                              const float* __restrict__ Wp,
                                              const float* __restrict__ bias_pool,
                                              const float* __restrict__ mlp_w,
                                              const float* __restrict__ mlp_b,
                                              float* __restrict__ out,
                                              int branch) {
    int n = blockIdx.x, tid = threadIdx.x, lane = tid & 63, wv = tid >> 6;
    __shared__ __align__(16) unsigned short lW[64 * 200];   // W^T: [o][kappa] pad->200
    __shared__ __align__(16) unsigned short lS[192 * 72];   // one source: [m][i] pad->72
    __shared__ float lBias[64];
    int q = lane >> 4, l15 = lane & 15;

    if (branch == 0) {
        float en[ED];
#pragma unroll
        for (int d = 0; d < ED; ++d) en[d] = E[n * ED + d];
        for (int idx = tid; idx < KC * OO; idx += 256) {
            int o = idx & 63, kap = idx >> 6;                  // kap = k*64+i
            float s = 0.f;
#pragma unroll
            for (int d = 0; d < ED; ++d) s += en[d] * Wp[((size_t)d * KC + kap) * OO + o];
            lW[o * 200 + kap] = f2bf(s);
        }
        if (tid < 64) {
            float s = 0.f;
#pragma unroll
            for (int d = 0; d < ED; ++d) s += en[d] * bias_pool[d * OO + tid];
            lBias[tid] = s;
        }
    } else {
        for (int idx = tid; idx < KC * OO; idx += 256) {
            int o = idx & 63, kap = idx >> 6;
            lW[o * 200 + kap] = f2bf(mlp_w[kap * OO + o]);
        }
        if (tid < 64) lBias[tid] = mlp_b[tid];
    }

    f32x4 zero = {0.f, 0.f, 0.f, 0.f};
    f32x4 acc[3][4];
#pragma unroll
    for (int a = 0; a < 3; ++a)
#pragma unroll
        for (int b = 0; b < 4; ++b) acc[a][b] = zero;

    const unsigned short* Ss[3] = { S0 + (size_t)n * JJ, S1 + (size_t)n * JJ, S2 + (size_t)n * JJ };

    for (int s = 0; s < 3; ++s) {
        __syncthreads();
        // stage source row: 12288 bf16 -> lS[m][i] (pad 72)
#pragma unroll
        for (int v = 0; v < 6; ++v) {
            int e8 = (v * 256 + tid) * 8;
            int m = e8 >> 6, i = e8 & 63;
            *(short8*)&lS[m * 72 + i] = *(const short8*)&Ss[s][e8];
        }
        __syncthreads();
#pragma unroll
        for (int h = 0; h < 2; ++h) {
            short8 af[3], bfr[4];
#pragma unroll
            for (int tm = 0; tm < 3; ++tm)
                af[tm] = *(const short8*)&lS[(wv * 48 + tm * 16 + l15) * 72 + h * 32 + q * 8];
#pragma unroll
            for (int tn = 0; tn < 4; ++tn)
                bfr[tn] = *(const short8*)&lW[(tn * 16 + l15) * 200 + s * 64 + h * 32 + q * 8];
#pragma unroll
            for (int tm = 0; tm < 3; ++tm)
#pragma unroll
                for (int tn = 0; tn < 4; ++tn)
                    acc[tm][tn] = __builtin_amdgcn_mfma_f32_16x16x32_bf16(af[tm], bfr[tn], acc[tm][tn], 0, 0, 0);
        }
    }
    // epilogue: out[b][o][n][t] fp32, m = b*T+t
#pragma unroll
    for (int tm = 0; tm < 3; ++tm) {
#pragma unroll
        for (int tn = 0; tn < 4; ++tn) {
            int o = tn * 16 + l15;
#pragma unroll
            for (int r = 0; r < 4; ++r) {
                int m = wv * 48 + tm * 16 + q * 4 + r;
                int b = m / TT, t = m - b * TT;
                out[(((size_t)b * OO + o) * NN + n) * TT + t] = acc[tm][tn][r] + lBias[o];
            }
        }
    }
}

// ---------------- launch ----------------
extern "C" void kernel_launch(void* const* d_in, const int* in_sizes, int n_in,
                              void* d_out, int out_size, void* d_ws, size_t ws_size,
                              hipStream_t stream) {
    const float* x         = (const float*)d_in[0];
    const float* node_emb  = (const float*)d_in[1];
    const float* support   = (const float*)d_in[2];
    const float* wpool     = (const float*)d_in[3];
    const float* bpool     = (const float*)d_in[4];
    const float* mlp_w     = (const float*)d_in[5];
    const float* mlp_b     = (const float*)d_in[6];
    float* out             = (float*)d_out;

    // workspace map (256 MB exactly):
    unsigned short* Abf = (unsigned short*)d_ws;                 // 8 MB
    unsigned short* Atb = Abf + (size_t)NN * NN;                 // 8 MB
    unsigned short* b1  = Atb + (size_t)NN * NN;                 // X2t          [j][n]
    unsigned short* b2  = b1 + (size_t)NJ;                       // X2           [n][j]
    unsigned short* b3  = b2 + (size_t)NJ;                       // Y1t / Z1t    [j][n]
    unsigned short* b4  = b3 + (size_t)NJ;                       // Y1 / Z1      [n][j]
    unsigned short* b5  = b4 + (size_t)NJ;                       // Y2 / Z2      [n][j]

    dim3 gg(96, 16);                 // GEMM grid
    dim3 gt(192, 32);                // transpose grid (64x64 tiles)

    // prep
    k_softmax_A<<<NN, 256, 0, stream>>>(node_emb, Abf);
    k_trans_bf<<<dim3(64, 64), dim3(32, 8), 0, stream>>>(support, Atb);
    k_make_X2<<<NJ / 256, 256, 0, stream>>>(x, b2);              // X2 [n][j]
    k_trans16<<<gt, 256, 0, stream>>>(b2, b1);                   // X2t [j][n]

    // adaptive branch
    k_gemm<<<gg, 256, 0, stream>>>(Abf, b1, b4, nullptr, 1.0f);  // Y1 = A*X2
    k_trans16<<<gt, 256, 0, stream>>>(b4, b3);                   // Y1t
    k_gemm<<<gg, 256, 0, stream>>>(Abf, b3, b5, b2, 2.0f);       // Y2 = 2*A*Y1 - X2
    k_node<<<NN, 256, 0, stream>>>(b2, b4, b5, node_emb, wpool, bpool, nullptr, nullptr,
                                   out, 0);

    // diffusion branch (reuses b3/b4/b5)
    k_gemm<<<gg, 256, 0, stream>>>(Atb, b1, b4, nullptr, 1.0f);  // Z1 = At*X2
    k_trans16<<<gt, 256, 0, stream>>>(b4, b3);                   // Z1t
    k_gemm<<<gg, 256, 0, stream>>>(Atb, b3, b5, nullptr, 1.0f);  // Z2 = At*Z1
    k_node<<<NN, 256, 0, stream>>>(b2, b4, b5, nullptr, nullptr, nullptr, mlp_w, mlp_b,
                                   out + (size_t)NJ, 1);
}